// Round 2
// baseline (822.504 us; speedup 1.0000x reference)
//
#include <hip/hip_runtime.h>

typedef unsigned int u32;
typedef unsigned short u16;
typedef unsigned long long u64;

// ---------------- workspace layout (floats) ----------------
#define REL_OFF   0
#define PTS4_OFF  1572864
#define ACC_OFF   1703936

__global__ __launch_bounds__(256) void prep_kernel(const float* __restrict__ xyz,
                                                   float4* __restrict__ pts4){
#pragma clang fp contract(off)
  int g = blockIdx.x*256 + threadIdx.x;
  int b = g >> 12, n = g & 4095;
  const float* xb = xyz + (size_t)b*12288;
  float x = xb[n], y = xb[4096+n], z = xb[8192+n];
  float sq = (x*x + y*y) + z*z;
  pts4[g] = make_float4(x,y,z,sq);
}

// 48-bit key = (order-mapped f32 dist << 16) | u16(4095 - j): descending value,
// ties -> lower index first (jax top_k order). Insert of 0 is a provable no-op
// (real keys >= 2^31 * 2^16 since dist >= 0).
__device__ __forceinline__ void chain_insert(u64* s, u64 key){
  #pragma unroll
  for (int t=0;t<17;t++){
    bool gt = key > s[t];
    u64 mx = gt ? key : s[t];
    key = gt ? s[t] : key;
    s[t] = mx;
  }
}

// One block = 64 queries of one batch; 8 waves; wave w scans candidates
// [w*512, w*512+512). Per-lane top-17 via gated LDS append + wave-synchronized
// register compare-swap chain. Then 8-way merge with 8 lanes per query.
__global__ __launch_bounds__(512, 4) void knn_kernel(const float4* __restrict__ pts4,
                                                     float* __restrict__ rel,
                                                     float* __restrict__ mom){
#pragma clang fp contract(off)
  __shared__ u32 lA[8704];   // phase1: [tid*16+i]=mapped bits ; phase2: [(w*17+i)*64+q]=key hi32
  __shared__ u16 lB[8704];   // phase1: u16(4095-j)            ; phase2: key lo16
  __shared__ float bmom[16];
  const int tid  = threadIdx.x;
  const int lane = tid & 63;
  const int wave = tid >> 6;
  const int blk  = blockIdx.x;         // 512 = 8 batches * 64 groups
  const int b    = blk >> 6;
  const int q0   = (blk & 63) << 6;
  const float4* __restrict__ P = pts4 + ((size_t)b << 12);
  const float4 me = P[q0 + lane];
  if (tid < 16) bmom[tid] = 0.0f;

  u64 s[17];
  #pragma unroll
  for (int i=0;i<17;i++) s[i] = 0ull;
  u32 kminhi = 0u;
  int cnt = 0;
  const int base = tid*16;
  const int j0 = __builtin_amdgcn_readfirstlane(wave << 9);

  float4 cur[8], nxt[8];
  #pragma unroll
  for (int u=0;u<8;u++) cur[u] = P[j0 + u];

  for (int g8 = 0; g8 < 512; g8 += 8){
    if (g8 + 8 < 512){
      #pragma unroll
      for (int u=0;u<8;u++) nxt[u] = P[j0 + g8 + 8 + u];   // wave-uniform -> s_load
    }
    #pragma unroll
    for (int u=0;u<8;u++){
      const int j = j0 + g8 + u;
      float dot = (me.x*cur[u].x + me.y*cur[u].y) + me.z*cur[u].z;
      float d   = (me.w + cur[u].w) - 2.0f*dot;
      u32 ub = __float_as_uint(d);
      ub ^= ((u32)(((int)ub) >> 31) | 0x80000000u);        // order-preserving map
      if (ub >= kminhi){                                    // conservative gate
        lA[base+cnt] = ub;
        lB[base+cnt] = (u16)(4095 - j);
        cnt++;
      }
    }
    if (__any(cnt >= 9)){            // cnt <= 16 always (8 pre + 8 new)
      int i = 0;
      while (__any(i < cnt)){
        u32 a = lA[base+i];
        u16 v = lB[base+i];
        u64 key = (i < cnt) ? (((u64)a << 16) | v) : 0ull;
        chain_insert(s, key);
        i++;
      }
      cnt = 0;
      kminhi = (u32)(s[16] >> 16);
    }
    #pragma unroll
    for (int u=0;u<8;u++) cur[u] = nxt[u];
  }
  { // final flush
    int i = 0;
    while (__any(i < cnt)){
      u32 a = lA[base+i];
      u16 v = lB[base+i];
      u64 key = (i < cnt) ? (((u64)a << 16) | v) : 0ull;
      chain_insert(s, key);
      i++;
    }
  }
  __syncthreads();                    // buffers dead; reuse LDS for sorted lists
  #pragma unroll
  for (int i=0;i<17;i++){
    const int o = ((wave*17 + i) << 6) + lane;
    lA[o] = (u32)(s[i] >> 16);
    lB[o] = (u16)s[i];
  }
  __syncthreads();

  // 8-way merge, 8 lanes per query (all 512 threads active).
  // Lists are disjoint candidate ranges -> keys unique, butterfly-max is exact.
  {
    const int q   = tid >> 3;
    const int sub = tid & 7;
    const float4 qp = P[q0 + q];
    float* __restrict__ ro = rel + (size_t)((b << 12) + q0 + q) * 48;
    float sm0=0,sm1=0,sm2=0,sm3=0,sm4=0,sm5=0,sm6=0,sm7=0,sm8=0;
    int p = 0;
    for (int r=0;r<17;r++){
      const int idx = ((sub*17 + p) << 6) + q;
      u64 mine = ((u64)lA[idx] << 16) | lB[idx];
      u64 kmax = mine;
      #pragma unroll
      for (int off=1; off<8; off<<=1){
        u64 o2 = __shfl_xor(kmax, off);
        kmax = (o2 > kmax) ? o2 : kmax;
      }
      p += (mine == kmax);
      if (r > 0 && sub == 0){   // drop rank 0 (the single farthest), keep 1..16
        const int j = 4095 - (int)(u32)(kmax & 0xFFFFull);
        const float4 nb = P[j];
        const float rx = nb.x - qp.x;
        const float ry = nb.y - qp.y;
        const float rz = nb.z - qp.z;
        ro[(r-1)*3+0] = rx; ro[(r-1)*3+1] = ry; ro[(r-1)*3+2] = rz;
        sm0 += rx; sm1 += ry; sm2 += rz;
        sm3 += rx*rx; sm4 += rx*ry; sm5 += rx*rz;
        sm6 += ry*ry; sm7 += ry*rz; sm8 += rz*rz;
      }
    }
    // sub0 lanes are 8 apart; butterfly over offsets 8/16/32 sums them per wave
    #pragma unroll
    for (int off=8; off<64; off<<=1){
      sm0 += __shfl_xor(sm0, off); sm1 += __shfl_xor(sm1, off); sm2 += __shfl_xor(sm2, off);
      sm3 += __shfl_xor(sm3, off); sm4 += __shfl_xor(sm4, off); sm5 += __shfl_xor(sm5, off);
      sm6 += __shfl_xor(sm6, off); sm7 += __shfl_xor(sm7, off); sm8 += __shfl_xor(sm8, off);
    }
    if (lane == 0){
      atomicAdd(&bmom[0], sm0); atomicAdd(&bmom[1], sm1); atomicAdd(&bmom[2], sm2);
      atomicAdd(&bmom[3], sm3); atomicAdd(&bmom[4], sm4); atomicAdd(&bmom[5], sm5);
      atomicAdd(&bmom[6], sm6); atomicAdd(&bmom[7], sm7); atomicAdd(&bmom[8], sm8);
    }
  }
  __syncthreads();
  if (tid < 9) atomicAdd(&mom[tid], bmom[tid]);
}

// BN1 stats analytically from rel moments: mean1 = w1*E[r]+b1, var1 = w1^T Cov(r) w1.
__global__ void stats1_kernel(const float* __restrict__ mom,
                              const float* __restrict__ w1, const float* __restrict__ b1,
                              const float* __restrict__ gamma, const float* __restrict__ beta,
                              float* __restrict__ s1, float* __restrict__ t1){
  const int o = threadIdx.x;           // 64 threads
  const float Minv = 1.0f / 524288.0f;
  float m0 = mom[0]*Minv, m1 = mom[1]*Minv, m2 = mom[2]*Minv;
  float cxx = mom[3]*Minv - m0*m0;
  float cxy = mom[4]*Minv - m0*m1;
  float cxz = mom[5]*Minv - m0*m2;
  float cyy = mom[6]*Minv - m1*m1;
  float cyz = mom[7]*Minv - m1*m2;
  float czz = mom[8]*Minv - m2*m2;
  float wx = w1[o*3+0], wy = w1[o*3+1], wz = w1[o*3+2];
  float mu  = wx*m0 + wy*m1 + wz*m2 + b1[o];
  float var = wx*wx*cxx + wy*wy*cyy + wz*wz*czz
            + 2.0f*(wx*wy*cxy + wx*wz*cxz + wy*wz*cyz);
  float istd = rsqrtf(var + 1e-5f);
  float g = gamma[o];
  s1[o] = g*istd;
  t1[o] = beta[o] - mu*g*istd;
}

// Pass 2: recompute h1, g2 = w2@h1+b2, accumulate per-channel sum/sumsq (BN2 stats).
__global__ __launch_bounds__(256) void pass2_kernel(const float* __restrict__ rel,
     const float* __restrict__ w1, const float* __restrict__ b1,
     const float* __restrict__ s1, const float* __restrict__ t1,
     const float* __restrict__ w2, const float* __restrict__ b2,
     float* __restrict__ gsum, float* __restrict__ gsq){
  __shared__ float lsum[64], lsq[64];
  const int tid = threadIdx.x;
  const int lane = tid & 63;
  if (tid < 64){ lsum[tid] = 0.0f; lsq[tid] = 0.0f; }
  __syncthreads();
  const size_t e = (size_t)blockIdx.x*256 + tid;
  const float rx = rel[e*3+0], ry = rel[e*3+1], rz = rel[e*3+2];
  float h1[64];
  #pragma unroll
  for (int o=0;o<64;o++){
    float g = fmaf(w1[o*3+0], rx, fmaf(w1[o*3+1], ry, fmaf(w1[o*3+2], rz, b1[o])));
    h1[o] = fmaxf(fmaf(g, s1[o], t1[o]), 0.0f);
  }
  for (int o=0;o<64;o++){
    const float* __restrict__ row = w2 + o*64;
    float a0=0,a1=0,a2=0,a3=0;
    #pragma unroll
    for (int c=0;c<64;c+=4){
      a0 = fmaf(row[c+0], h1[c+0], a0);
      a1 = fmaf(row[c+1], h1[c+1], a1);
      a2 = fmaf(row[c+2], h1[c+2], a2);
      a3 = fmaf(row[c+3], h1[c+3], a3);
    }
    float g2 = ((a0+a1)+(a2+a3)) + b2[o];
    float q2 = g2*g2;
    #pragma unroll
    for (int off=32; off>0; off>>=1){
      g2 += __shfl_down(g2, off);
      q2 += __shfl_down(q2, off);
    }
    if (lane == 0){ atomicAdd(&lsum[o], g2); atomicAdd(&lsq[o], q2); }
  }
  __syncthreads();
  if (tid < 64){ atomicAdd(&gsum[tid], lsum[tid]); atomicAdd(&gsq[tid], lsq[tid]); }
}

__global__ void stats2_kernel(const float* __restrict__ gsum, const float* __restrict__ gsq,
                              const float* __restrict__ gamma, const float* __restrict__ beta,
                              float* __restrict__ s2, float* __restrict__ t2){
  const int o = threadIdx.x;
  const float Minv = 1.0f / 524288.0f;
  float mu  = gsum[o]*Minv;
  float var = gsq[o]*Minv - mu*mu;
  float istd = rsqrtf(var + 1e-5f);
  float g = gamma[o];
  s2[o] = g*istd;
  t2[o] = beta[o] - mu*g*istd;
}

// Pass 3: h1 -> h2 -> g3, max over k (lanes grouped 16 per point), write out[b][o][n].
__global__ __launch_bounds__(256) void pass3_kernel(const float* __restrict__ rel,
     const float* __restrict__ w1, const float* __restrict__ b1,
     const float* __restrict__ s1, const float* __restrict__ t1,
     const float* __restrict__ w2, const float* __restrict__ b2,
     const float* __restrict__ s2, const float* __restrict__ t2,
     float* __restrict__ out){
  const int tid  = threadIdx.x;
  const int lane = tid & 63;
  const size_t e = (size_t)blockIdx.x*256 + tid;
  const int b = (int)(e >> 16);
  const int n = (int)((e >> 4) & 4095);
  const float rx = rel[e*3+0], ry = rel[e*3+1], rz = rel[e*3+2];
  float h1[64];
  #pragma unroll
  for (int o=0;o<64;o++){
    float g = fmaf(w1[o*3+0], rx, fmaf(w1[o*3+1], ry, fmaf(w1[o*3+2], rz, b1[o])));
    h1[o] = fmaxf(fmaf(g, s1[o], t1[o]), 0.0f);
  }
  float h2[64];
  for (int o=0;o<64;o++){
    const float* __restrict__ row = w2 + o*64;
    float a0=0,a1=0,a2=0,a3=0;
    #pragma unroll
    for (int c=0;c<64;c+=4){
      a0 = fmaf(row[c+0], h1[c+0], a0);
      a1 = fmaf(row[c+1], h1[c+1], a1);
      a2 = fmaf(row[c+2], h1[c+2], a2);
      a3 = fmaf(row[c+3], h1[c+3], a3);
    }
    float g2 = ((a0+a1)+(a2+a3)) + b2[o];
    h2[o] = fmaxf(fmaf(g2, s2[o], t2[o]), 0.0f);
  }
  for (int o=0;o<64;o++){
    const float* __restrict__ row = w2 + o*64;
    float a0=0,a1=0,a2=0,a3=0;
    #pragma unroll
    for (int c=0;c<64;c+=4){
      a0 = fmaf(row[c+0], h2[c+0], a0);
      a1 = fmaf(row[c+1], h2[c+1], a1);
      a2 = fmaf(row[c+2], h2[c+2], a2);
      a3 = fmaf(row[c+3], h2[c+3], a3);
    }
    float g3 = ((a0+a1)+(a2+a3)) + b2[o];
    g3 = fmaxf(g3, __shfl_xor(g3, 1));
    g3 = fmaxf(g3, __shfl_xor(g3, 2));
    g3 = fmaxf(g3, __shfl_xor(g3, 4));
    g3 = fmaxf(g3, __shfl_xor(g3, 8));
    if ((lane & 15) == 0){
      out[(((size_t)b*64 + o) << 12) + n] = g3;
    }
  }
}

extern "C" void kernel_launch(void* const* d_in, const int* in_sizes, int n_in,
                              void* d_out, int out_size, void* d_ws, size_t ws_size,
                              hipStream_t stream){
  const float* xyz   = (const float*)d_in[0];
  const float* w1    = (const float*)d_in[1];
  const float* b1    = (const float*)d_in[2];
  const float* w2    = (const float*)d_in[3];
  const float* b2    = (const float*)d_in[4];
  const float* gamma = (const float*)d_in[5];
  const float* beta  = (const float*)d_in[6];
  float* out = (float*)d_out;
  float* ws  = (float*)d_ws;

  float*  rel  = ws + REL_OFF;
  float4* pts4 = (float4*)(ws + PTS4_OFF);
  float*  mom  = ws + ACC_OFF;        // 9 used (padded to 16)
  float*  gsum = mom + 16;            // 64
  float*  gsq  = mom + 80;            // 64
  float*  s1   = ws + 1704080;
  float*  t1   = ws + 1704144;
  float*  s2   = ws + 1704208;
  float*  t2   = ws + 1704272;

  hipMemsetAsync(mom, 0, 144*sizeof(float), stream);
  prep_kernel  <<<128,  256, 0, stream>>>(xyz, pts4);
  knn_kernel   <<<512,  512, 0, stream>>>(pts4, rel, mom);
  stats1_kernel<<<1,     64, 0, stream>>>(mom, w1, b1, gamma, beta, s1, t1);
  pass2_kernel <<<2048, 256, 0, stream>>>(rel, w1, b1, s1, t1, w2, b2, gsum, gsq);
  stats2_kernel<<<1,     64, 0, stream>>>(gsum, gsq, gamma, beta, s2, t2);
  pass3_kernel <<<2048, 256, 0, stream>>>(rel, w1, b1, s1, t1, w2, b2, s2, t2, out);
}

// Round 3
// 749.945 us; speedup vs baseline: 1.0968x; 1.0968x over previous
//
#include <hip/hip_runtime.h>

typedef unsigned int u32;
typedef unsigned short u16;
typedef unsigned long long u64;

// ---------------- workspace layout (floats) ----------------
#define REL_OFF   0
#define PTS4_OFF  1572864
#define ACC_OFF   1703936

__global__ __launch_bounds__(256) void prep_kernel(const float* __restrict__ xyz,
                                                   float4* __restrict__ pts4){
#pragma clang fp contract(off)
  int g = blockIdx.x*256 + threadIdx.x;
  int b = g >> 12, n = g & 4095;
  const float* xb = xyz + (size_t)b*12288;
  float x = xb[n], y = xb[4096+n], z = xb[8192+n];
  float sq = (x*x + y*y) + z*z;
  pts4[g] = make_float4(x,y,z,sq);
}

// 48-bit key = (order-mapped f32 dist << 16) | u16(4095 - j): descending value,
// ties -> lower index first (jax top_k order). Insert of 0 is a provable no-op
// (real keys >= 2^31 * 2^16 since dist >= 0).
__device__ __forceinline__ void chain_insert(u64* s, u64 key){
  #pragma unroll
  for (int t=0;t<17;t++){
    bool gt = key > s[t];
    u64 mx = gt ? key : s[t];
    key = gt ? s[t] : key;
    s[t] = mx;
  }
}

// One block = 64 queries of one batch; 8 waves; wave w scans candidates
// [w*512, w*512+512). Per-lane top-17 via gated LDS append (stride 17 words:
// odd -> bank-conflict-free) + wave-synchronized register compare-swap chain.
// Then 8-way merge with 8 lanes per query (phase-2 list stride 65).
// NOTE round-2 lessons: no double-buffer (spilled 229MB scratch), no stride-16
// LDS (30M bank conflicts).
__global__ __launch_bounds__(512, 2) void knn_kernel(const float4* __restrict__ pts4,
                                                     float* __restrict__ rel,
                                                     float* __restrict__ mom){
#pragma clang fp contract(off)
  __shared__ u32 lA[8840];   // phase1: [tid*17+i]=mapped bits ; phase2: [(w*17+i)*65+q]=key hi32
  __shared__ u16 lB[8840];   // phase1: u16(4095-j)            ; phase2: key lo16
  __shared__ float bmom[16];
  const int tid  = threadIdx.x;
  const int lane = tid & 63;
  const int wave = tid >> 6;
  const int blk  = blockIdx.x;         // 512 = 8 batches * 64 groups
  const int b    = blk >> 6;
  const int q0   = (blk & 63) << 6;
  const float4* __restrict__ P = pts4 + ((size_t)b << 12);
  const float4 me = P[q0 + lane];
  if (tid < 16) bmom[tid] = 0.0f;

  u64 s[17];
  #pragma unroll
  for (int i=0;i<17;i++) s[i] = 0ull;
  u32 kminhi = 0u;
  int cnt = 0;
  const int base = tid*17;
  const int j0 = __builtin_amdgcn_readfirstlane(wave << 9);

  for (int g8 = 0; g8 < 512; g8 += 8){
    float4 c[8];
    #pragma unroll
    for (int u=0;u<8;u++) c[u] = P[j0 + g8 + u];   // wave-uniform -> s_load
    #pragma unroll
    for (int u=0;u<8;u++){
      const int j = j0 + g8 + u;
      float dot = (me.x*c[u].x + me.y*c[u].y) + me.z*c[u].z;
      float d   = (me.w + c[u].w) - 2.0f*dot;
      u32 ub = __float_as_uint(d);
      ub ^= ((u32)(((int)ub) >> 31) | 0x80000000u);        // order-preserving map
      if (ub >= kminhi){                                    // conservative gate
        lA[base+cnt] = ub;
        lB[base+cnt] = (u16)(4095 - j);
        cnt++;
      }
    }
    if (__any(cnt >= 9)){            // cnt <= 16 always (8 pre + 8 new)
      int i = 0;
      while (__any(i < cnt)){
        u32 a = lA[base+i];
        u16 v = lB[base+i];
        u64 key = (i < cnt) ? (((u64)a << 16) | v) : 0ull;
        chain_insert(s, key);
        i++;
      }
      cnt = 0;
      kminhi = (u32)(s[16] >> 16);
    }
  }
  { // final flush
    int i = 0;
    while (__any(i < cnt)){
      u32 a = lA[base+i];
      u16 v = lB[base+i];
      u64 key = (i < cnt) ? (((u64)a << 16) | v) : 0ull;
      chain_insert(s, key);
      i++;
    }
  }
  __syncthreads();                    // buffers dead; reuse LDS for sorted lists
  #pragma unroll
  for (int i=0;i<17;i++){
    const int o = (wave*17 + i)*65 + lane;
    lA[o] = (u32)(s[i] >> 16);
    lB[o] = (u16)s[i];
  }
  __syncthreads();

  // 8-way merge, 8 lanes per query (all 512 threads active).
  // Lists are disjoint candidate ranges -> keys unique, butterfly-max is exact.
  {
    const int q   = tid >> 3;
    const int sub = tid & 7;
    const float4 qp = P[q0 + q];
    float* __restrict__ ro = rel + (size_t)((b << 12) + q0 + q) * 48;
    float sm0=0,sm1=0,sm2=0,sm3=0,sm4=0,sm5=0,sm6=0,sm7=0,sm8=0;
    int p = 0;
    for (int r=0;r<17;r++){
      const int idx = (sub*17 + p)*65 + q;
      u64 mine = ((u64)lA[idx] << 16) | lB[idx];
      u64 kmax = mine;
      #pragma unroll
      for (int off=1; off<8; off<<=1){
        u64 o2 = __shfl_xor(kmax, off);
        kmax = (o2 > kmax) ? o2 : kmax;
      }
      p += (mine == kmax);
      if (r > 0 && sub == 0){   // drop rank 0 (the single farthest), keep 1..16
        const int j = 4095 - (int)(u32)(kmax & 0xFFFFull);
        const float4 nb = P[j];
        const float rx = nb.x - qp.x;
        const float ry = nb.y - qp.y;
        const float rz = nb.z - qp.z;
        ro[(r-1)*3+0] = rx; ro[(r-1)*3+1] = ry; ro[(r-1)*3+2] = rz;
        sm0 += rx; sm1 += ry; sm2 += rz;
        sm3 += rx*rx; sm4 += rx*ry; sm5 += rx*rz;
        sm6 += ry*ry; sm7 += ry*rz; sm8 += rz*rz;
      }
    }
    // sub0 lanes are 8 apart; butterfly over offsets 8/16/32 sums them per wave
    #pragma unroll
    for (int off=8; off<64; off<<=1){
      sm0 += __shfl_xor(sm0, off); sm1 += __shfl_xor(sm1, off); sm2 += __shfl_xor(sm2, off);
      sm3 += __shfl_xor(sm3, off); sm4 += __shfl_xor(sm4, off); sm5 += __shfl_xor(sm5, off);
      sm6 += __shfl_xor(sm6, off); sm7 += __shfl_xor(sm7, off); sm8 += __shfl_xor(sm8, off);
    }
    if (lane == 0){
      atomicAdd(&bmom[0], sm0); atomicAdd(&bmom[1], sm1); atomicAdd(&bmom[2], sm2);
      atomicAdd(&bmom[3], sm3); atomicAdd(&bmom[4], sm4); atomicAdd(&bmom[5], sm5);
      atomicAdd(&bmom[6], sm6); atomicAdd(&bmom[7], sm7); atomicAdd(&bmom[8], sm8);
    }
  }
  __syncthreads();
  if (tid < 9) atomicAdd(&mom[tid], bmom[tid]);
}

// BN1 stats analytically from rel moments: mean1 = w1*E[r]+b1, var1 = w1^T Cov(r) w1.
__global__ void stats1_kernel(const float* __restrict__ mom,
                              const float* __restrict__ w1, const float* __restrict__ b1,
                              const float* __restrict__ gamma, const float* __restrict__ beta,
                              float* __restrict__ s1, float* __restrict__ t1){
  const int o = threadIdx.x;           // 64 threads
  const float Minv = 1.0f / 524288.0f;
  float m0 = mom[0]*Minv, m1 = mom[1]*Minv, m2 = mom[2]*Minv;
  float cxx = mom[3]*Minv - m0*m0;
  float cxy = mom[4]*Minv - m0*m1;
  float cxz = mom[5]*Minv - m0*m2;
  float cyy = mom[6]*Minv - m1*m1;
  float cyz = mom[7]*Minv - m1*m2;
  float czz = mom[8]*Minv - m2*m2;
  float wx = w1[o*3+0], wy = w1[o*3+1], wz = w1[o*3+2];
  float mu  = wx*m0 + wy*m1 + wz*m2 + b1[o];
  float var = wx*wx*cxx + wy*wy*cyy + wz*wz*czz
            + 2.0f*(wx*wy*cxy + wx*wz*cxz + wy*wz*cyz);
  float istd = rsqrtf(var + 1e-5f);
  float g = gamma[o];
  s1[o] = g*istd;
  t1[o] = beta[o] - mu*g*istd;
}

// Pass 2: recompute h1, g2 = w2@h1+b2, accumulate per-channel sum/sumsq (BN2 stats).
__global__ __launch_bounds__(256) void pass2_kernel(const float* __restrict__ rel,
     const float* __restrict__ w1, const float* __restrict__ b1,
     const float* __restrict__ s1, const float* __restrict__ t1,
     const float* __restrict__ w2, const float* __restrict__ b2,
     float* __restrict__ gsum, float* __restrict__ gsq){
  __shared__ float lsum[64], lsq[64];
  const int tid = threadIdx.x;
  const int lane = tid & 63;
  if (tid < 64){ lsum[tid] = 0.0f; lsq[tid] = 0.0f; }
  __syncthreads();
  const size_t e = (size_t)blockIdx.x*256 + tid;
  const float rx = rel[e*3+0], ry = rel[e*3+1], rz = rel[e*3+2];
  float h1[64];
  #pragma unroll
  for (int o=0;o<64;o++){
    float g = fmaf(w1[o*3+0], rx, fmaf(w1[o*3+1], ry, fmaf(w1[o*3+2], rz, b1[o])));
    h1[o] = fmaxf(fmaf(g, s1[o], t1[o]), 0.0f);
  }
  for (int o=0;o<64;o++){
    const float* __restrict__ row = w2 + o*64;
    float a0=0,a1=0,a2=0,a3=0;
    #pragma unroll
    for (int c=0;c<64;c+=4){
      a0 = fmaf(row[c+0], h1[c+0], a0);
      a1 = fmaf(row[c+1], h1[c+1], a1);
      a2 = fmaf(row[c+2], h1[c+2], a2);
      a3 = fmaf(row[c+3], h1[c+3], a3);
    }
    float g2 = ((a0+a1)+(a2+a3)) + b2[o];
    float q2 = g2*g2;
    #pragma unroll
    for (int off=32; off>0; off>>=1){
      g2 += __shfl_down(g2, off);
      q2 += __shfl_down(q2, off);
    }
    if (lane == 0){ atomicAdd(&lsum[o], g2); atomicAdd(&lsq[o], q2); }
  }
  __syncthreads();
  if (tid < 64){ atomicAdd(&gsum[tid], lsum[tid]); atomicAdd(&gsq[tid], lsq[tid]); }
}

__global__ void stats2_kernel(const float* __restrict__ gsum, const float* __restrict__ gsq,
                              const float* __restrict__ gamma, const float* __restrict__ beta,
                              float* __restrict__ s2, float* __restrict__ t2){
  const int o = threadIdx.x;
  const float Minv = 1.0f / 524288.0f;
  float mu  = gsum[o]*Minv;
  float var = gsq[o]*Minv - mu*mu;
  float istd = rsqrtf(var + 1e-5f);
  float g = gamma[o];
  s2[o] = g*istd;
  t2[o] = beta[o] - mu*g*istd;
}

// Pass 3: h1 -> h2 -> g3, max over k (lanes grouped 16 per point), write out[b][o][n].
__global__ __launch_bounds__(256) void pass3_kernel(const float* __restrict__ rel,
     const float* __restrict__ w1, const float* __restrict__ b1,
     const float* __restrict__ s1, const float* __restrict__ t1,
     const float* __restrict__ w2, const float* __restrict__ b2,
     const float* __restrict__ s2, const float* __restrict__ t2,
     float* __restrict__ out){
  const int tid  = threadIdx.x;
  const int lane = tid & 63;
  const size_t e = (size_t)blockIdx.x*256 + tid;
  const int b = (int)(e >> 16);
  const int n = (int)((e >> 4) & 4095);
  const float rx = rel[e*3+0], ry = rel[e*3+1], rz = rel[e*3+2];
  float h1[64];
  #pragma unroll
  for (int o=0;o<64;o++){
    float g = fmaf(w1[o*3+0], rx, fmaf(w1[o*3+1], ry, fmaf(w1[o*3+2], rz, b1[o])));
    h1[o] = fmaxf(fmaf(g, s1[o], t1[o]), 0.0f);
  }
  float h2[64];
  for (int o=0;o<64;o++){
    const float* __restrict__ row = w2 + o*64;
    float a0=0,a1=0,a2=0,a3=0;
    #pragma unroll
    for (int c=0;c<64;c+=4){
      a0 = fmaf(row[c+0], h1[c+0], a0);
      a1 = fmaf(row[c+1], h1[c+1], a1);
      a2 = fmaf(row[c+2], h1[c+2], a2);
      a3 = fmaf(row[c+3], h1[c+3], a3);
    }
    float g2 = ((a0+a1)+(a2+a3)) + b2[o];
    h2[o] = fmaxf(fmaf(g2, s2[o], t2[o]), 0.0f);
  }
  for (int o=0;o<64;o++){
    const float* __restrict__ row = w2 + o*64;
    float a0=0,a1=0,a2=0,a3=0;
    #pragma unroll
    for (int c=0;c<64;c+=4){
      a0 = fmaf(row[c+0], h2[c+0], a0);
      a1 = fmaf(row[c+1], h2[c+1], a1);
      a2 = fmaf(row[c+2], h2[c+2], a2);
      a3 = fmaf(row[c+3], h2[c+3], a3);
    }
    float g3 = ((a0+a1)+(a2+a3)) + b2[o];
    g3 = fmaxf(g3, __shfl_xor(g3, 1));
    g3 = fmaxf(g3, __shfl_xor(g3, 2));
    g3 = fmaxf(g3, __shfl_xor(g3, 4));
    g3 = fmaxf(g3, __shfl_xor(g3, 8));
    if ((lane & 15) == 0){
      out[(((size_t)b*64 + o) << 12) + n] = g3;
    }
  }
}

extern "C" void kernel_launch(void* const* d_in, const int* in_sizes, int n_in,
                              void* d_out, int out_size, void* d_ws, size_t ws_size,
                              hipStream_t stream){
  const float* xyz   = (const float*)d_in[0];
  const float* w1    = (const float*)d_in[1];
  const float* b1    = (const float*)d_in[2];
  const float* w2    = (const float*)d_in[3];
  const float* b2    = (const float*)d_in[4];
  const float* gamma = (const float*)d_in[5];
  const float* beta  = (const float*)d_in[6];
  float* out = (float*)d_out;
  float* ws  = (float*)d_ws;

  float*  rel  = ws + REL_OFF;
  float4* pts4 = (float4*)(ws + PTS4_OFF);
  float*  mom  = ws + ACC_OFF;        // 9 used (padded to 16)
  float*  gsum = mom + 16;            // 64
  float*  gsq  = mom + 80;            // 64
  float*  s1   = ws + 1704080;
  float*  t1   = ws + 1704144;
  float*  s2   = ws + 1704208;
  float*  t2   = ws + 1704272;

  hipMemsetAsync(mom, 0, 144*sizeof(float), stream);
  prep_kernel  <<<128,  256, 0, stream>>>(xyz, pts4);
  knn_kernel   <<<512,  512, 0, stream>>>(pts4, rel, mom);
  stats1_kernel<<<1,     64, 0, stream>>>(mom, w1, b1, gamma, beta, s1, t1);
  pass2_kernel <<<2048, 256, 0, stream>>>(rel, w1, b1, s1, t1, w2, b2, gsum, gsq);
  stats2_kernel<<<1,     64, 0, stream>>>(gsum, gsq, gamma, beta, s2, t2);
  pass3_kernel <<<2048, 256, 0, stream>>>(rel, w1, b1, s1, t1, w2, b2, s2, t2, out);
}

// Round 4
// 700.840 us; speedup vs baseline: 1.1736x; 1.0701x over previous
//
#include <hip/hip_runtime.h>

typedef unsigned int u32;
typedef unsigned short u16;
typedef unsigned long long u64;

// ---------------- workspace layout (floats) ----------------
#define REL_OFF   0
#define PTS4_OFF  1572864
#define ACC_OFF   1703936

__global__ __launch_bounds__(256) void prep_kernel(const float* __restrict__ xyz,
                                                   float4* __restrict__ pts4){
#pragma clang fp contract(off)
  int g = blockIdx.x*256 + threadIdx.x;
  int b = g >> 12, n = g & 4095;
  const float* xb = xyz + (size_t)b*12288;
  float x = xb[n], y = xb[4096+n], z = xb[8192+n];
  float sq = (x*x + y*y) + z*z;
  pts4[g] = make_float4(x,y,z,sq);
}

// 48-bit key = (order-mapped f32 dist << 16) | u16(4095 - j): descending value,
// ties -> lower index first (jax top_k order). Insert of 0 is a provable no-op
// (real keys >= 2^31 * 2^16 since dist >= 0).
__device__ __forceinline__ void chain_insert(u64* s, u64 key){
  #pragma unroll
  for (int t=0;t<17;t++){
    bool gt = key > s[t];
    u64 mx = gt ? key : s[t];
    key = gt ? s[t] : key;
    s[t] = mx;
  }
}

// One block = 64 queries of one batch; 8 waves; wave w scans candidates
// [w*512, w*512+512). Per-lane top-17 via gated LDS append (stride 17 words:
// odd -> bank-conflict-free) + wave-synchronized register compare-swap chain.
// ROUND-4 change: per-query gate SHARED across the 8 waves via LDS atomicMax.
// Any wave's local-17th dist is a lower bound on the global-17th dist, so the
// max over published bounds is a tighter (still conservative, tie-safe via >=)
// append gate: ~5x fewer chain inserts, which round-3 counters showed dominate.
// Items evicted from a chain always have 17 locally-better items, so eviction
// never loses a global-top-17 member regardless of gate tightness.
__global__ __launch_bounds__(512, 2) void knn_kernel(const float4* __restrict__ pts4,
                                                     float* __restrict__ rel,
                                                     float* __restrict__ mom){
#pragma clang fp contract(off)
  __shared__ u32 lA[8840];   // phase1: [tid*17+i]=mapped bits ; phase2: [(w*17+i)*65+q]=key hi32
  __shared__ u16 lB[8840];   // phase1: u16(4095-j)            ; phase2: key lo16
  __shared__ float bmom[16];
  __shared__ u32 gate[64];   // per-query shared lower bound on global-17th dist bits
  const int tid  = threadIdx.x;
  const int lane = tid & 63;
  const int wave = tid >> 6;
  const int blk  = blockIdx.x;         // 512 = 8 batches * 64 groups
  const int b    = blk >> 6;
  const int q0   = (blk & 63) << 6;
  const float4* __restrict__ P = pts4 + ((size_t)b << 12);
  const float4 me = P[q0 + lane];
  if (tid < 16) bmom[tid] = 0.0f;
  if (tid < 64) gate[tid] = 0u;
  __syncthreads();                     // gate/bmom init visible to all waves

  u64 s[17];
  #pragma unroll
  for (int i=0;i<17;i++) s[i] = 0ull;
  u32 kminhi = 0u;
  int cnt = 0;
  const int base = tid*17;
  const int j0 = __builtin_amdgcn_readfirstlane(wave << 9);

  for (int g8 = 0; g8 < 512; g8 += 8){
    kminhi = max(kminhi, gate[lane]);              // adopt block-wide bound (monotone)
    float4 c[8];
    #pragma unroll
    for (int u=0;u<8;u++) c[u] = P[j0 + g8 + u];   // wave-uniform -> s_load
    #pragma unroll
    for (int u=0;u<8;u++){
      const int j = j0 + g8 + u;
      float dot = (me.x*c[u].x + me.y*c[u].y) + me.z*c[u].z;
      float d   = (me.w + c[u].w) - 2.0f*dot;
      u32 ub = __float_as_uint(d);
      ub ^= ((u32)(((int)ub) >> 31) | 0x80000000u);        // order-preserving map
      if (ub >= kminhi){                                    // conservative gate
        lA[base+cnt] = ub;
        lB[base+cnt] = (u16)(4095 - j);
        cnt++;
      }
    }
    if (__any(cnt >= 9)){            // cnt <= 16 always (8 pre + 8 new)
      int i = 0;
      while (__any(i < cnt)){
        u32 a = lA[base+i];
        u16 v = lB[base+i];
        u64 key = (i < cnt) ? (((u64)a << 16) | v) : 0ull;
        chain_insert(s, key);
        i++;
      }
      cnt = 0;
      // publish our local-17th bound; re-read the block max (>= own, conservative)
      u32 own = (u32)(s[16] >> 16);
      if (own) atomicMax(&gate[lane], own);
      kminhi = max(kminhi, own);
    }
  }
  { // final flush
    int i = 0;
    while (__any(i < cnt)){
      u32 a = lA[base+i];
      u16 v = lB[base+i];
      u64 key = (i < cnt) ? (((u64)a << 16) | v) : 0ull;
      chain_insert(s, key);
      i++;
    }
  }
  __syncthreads();                    // buffers dead; reuse LDS for sorted lists
  #pragma unroll
  for (int i=0;i<17;i++){
    const int o = (wave*17 + i)*65 + lane;
    lA[o] = (u32)(s[i] >> 16);
    lB[o] = (u16)s[i];
  }
  __syncthreads();

  // 8-way merge, 8 lanes per query (all 512 threads active).
  // Lists are disjoint candidate ranges -> keys unique, butterfly-max is exact.
  // Partially-filled lists contain 0-keys which never win before round 17.
  {
    const int q   = tid >> 3;
    const int sub = tid & 7;
    const float4 qp = P[q0 + q];
    float* __restrict__ ro = rel + (size_t)((b << 12) + q0 + q) * 48;
    float sm0=0,sm1=0,sm2=0,sm3=0,sm4=0,sm5=0,sm6=0,sm7=0,sm8=0;
    int p = 0;
    for (int r=0;r<17;r++){
      const int idx = (sub*17 + p)*65 + q;
      u64 mine = ((u64)lA[idx] << 16) | lB[idx];
      u64 kmax = mine;
      #pragma unroll
      for (int off=1; off<8; off<<=1){
        u64 o2 = __shfl_xor(kmax, off);
        kmax = (o2 > kmax) ? o2 : kmax;
      }
      p += (mine == kmax);
      if (r > 0 && sub == 0){   // drop rank 0 (the single farthest), keep 1..16
        const int j = 4095 - (int)(u32)(kmax & 0xFFFFull);
        const float4 nb = P[j];
        const float rx = nb.x - qp.x;
        const float ry = nb.y - qp.y;
        const float rz = nb.z - qp.z;
        ro[(r-1)*3+0] = rx; ro[(r-1)*3+1] = ry; ro[(r-1)*3+2] = rz;
        sm0 += rx; sm1 += ry; sm2 += rz;
        sm3 += rx*rx; sm4 += rx*ry; sm5 += rx*rz;
        sm6 += ry*ry; sm7 += ry*rz; sm8 += rz*rz;
      }
    }
    // sub0 lanes are 8 apart; butterfly over offsets 8/16/32 sums them per wave
    #pragma unroll
    for (int off=8; off<64; off<<=1){
      sm0 += __shfl_xor(sm0, off); sm1 += __shfl_xor(sm1, off); sm2 += __shfl_xor(sm2, off);
      sm3 += __shfl_xor(sm3, off); sm4 += __shfl_xor(sm4, off); sm5 += __shfl_xor(sm5, off);
      sm6 += __shfl_xor(sm6, off); sm7 += __shfl_xor(sm7, off); sm8 += __shfl_xor(sm8, off);
    }
    if (lane == 0){
      atomicAdd(&bmom[0], sm0); atomicAdd(&bmom[1], sm1); atomicAdd(&bmom[2], sm2);
      atomicAdd(&bmom[3], sm3); atomicAdd(&bmom[4], sm4); atomicAdd(&bmom[5], sm5);
      atomicAdd(&bmom[6], sm6); atomicAdd(&bmom[7], sm7); atomicAdd(&bmom[8], sm8);
    }
  }
  __syncthreads();
  if (tid < 9) atomicAdd(&mom[tid], bmom[tid]);
}

// BN1 stats analytically from rel moments: mean1 = w1*E[r]+b1, var1 = w1^T Cov(r) w1.
__global__ void stats1_kernel(const float* __restrict__ mom,
                              const float* __restrict__ w1, const float* __restrict__ b1,
                              const float* __restrict__ gamma, const float* __restrict__ beta,
                              float* __restrict__ s1, float* __restrict__ t1){
  const int o = threadIdx.x;           // 64 threads
  const float Minv = 1.0f / 524288.0f;
  float m0 = mom[0]*Minv, m1 = mom[1]*Minv, m2 = mom[2]*Minv;
  float cxx = mom[3]*Minv - m0*m0;
  float cxy = mom[4]*Minv - m0*m1;
  float cxz = mom[5]*Minv - m0*m2;
  float cyy = mom[6]*Minv - m1*m1;
  float cyz = mom[7]*Minv - m1*m2;
  float czz = mom[8]*Minv - m2*m2;
  float wx = w1[o*3+0], wy = w1[o*3+1], wz = w1[o*3+2];
  float mu  = wx*m0 + wy*m1 + wz*m2 + b1[o];
  float var = wx*wx*cxx + wy*wy*cyy + wz*wz*czz
            + 2.0f*(wx*wy*cxy + wx*wz*cxz + wy*wz*cyz);
  float istd = rsqrtf(var + 1e-5f);
  float g = gamma[o];
  s1[o] = g*istd;
  t1[o] = beta[o] - mu*g*istd;
}

// Pass 2: recompute h1, g2 = w2@h1+b2, accumulate per-channel sum/sumsq (BN2 stats).
__global__ __launch_bounds__(256) void pass2_kernel(const float* __restrict__ rel,
     const float* __restrict__ w1, const float* __restrict__ b1,
     const float* __restrict__ s1, const float* __restrict__ t1,
     const float* __restrict__ w2, const float* __restrict__ b2,
     float* __restrict__ gsum, float* __restrict__ gsq){
  __shared__ float lsum[64], lsq[64];
  const int tid = threadIdx.x;
  const int lane = tid & 63;
  if (tid < 64){ lsum[tid] = 0.0f; lsq[tid] = 0.0f; }
  __syncthreads();
  const size_t e = (size_t)blockIdx.x*256 + tid;
  const float rx = rel[e*3+0], ry = rel[e*3+1], rz = rel[e*3+2];
  float h1[64];
  #pragma unroll
  for (int o=0;o<64;o++){
    float g = fmaf(w1[o*3+0], rx, fmaf(w1[o*3+1], ry, fmaf(w1[o*3+2], rz, b1[o])));
    h1[o] = fmaxf(fmaf(g, s1[o], t1[o]), 0.0f);
  }
  for (int o=0;o<64;o++){
    const float* __restrict__ row = w2 + o*64;
    float a0=0,a1=0,a2=0,a3=0;
    #pragma unroll
    for (int c=0;c<64;c+=4){
      a0 = fmaf(row[c+0], h1[c+0], a0);
      a1 = fmaf(row[c+1], h1[c+1], a1);
      a2 = fmaf(row[c+2], h1[c+2], a2);
      a3 = fmaf(row[c+3], h1[c+3], a3);
    }
    float g2 = ((a0+a1)+(a2+a3)) + b2[o];
    float q2 = g2*g2;
    #pragma unroll
    for (int off=32; off>0; off>>=1){
      g2 += __shfl_down(g2, off);
      q2 += __shfl_down(q2, off);
    }
    if (lane == 0){ atomicAdd(&lsum[o], g2); atomicAdd(&lsq[o], q2); }
  }
  __syncthreads();
  if (tid < 64){ atomicAdd(&gsum[tid], lsum[tid]); atomicAdd(&gsq[tid], lsq[tid]); }
}

__global__ void stats2_kernel(const float* __restrict__ gsum, const float* __restrict__ gsq,
                              const float* __restrict__ gamma, const float* __restrict__ beta,
                              float* __restrict__ s2, float* __restrict__ t2){
  const int o = threadIdx.x;
  const float Minv = 1.0f / 524288.0f;
  float mu  = gsum[o]*Minv;
  float var = gsq[o]*Minv - mu*mu;
  float istd = rsqrtf(var + 1e-5f);
  float g = gamma[o];
  s2[o] = g*istd;
  t2[o] = beta[o] - mu*g*istd;
}

// Pass 3: h1 -> h2 -> g3, max over k (lanes grouped 16 per point), write out[b][o][n].
__global__ __launch_bounds__(256) void pass3_kernel(const float* __restrict__ rel,
     const float* __restrict__ w1, const float* __restrict__ b1,
     const float* __restrict__ s1, const float* __restrict__ t1,
     const float* __restrict__ w2, const float* __restrict__ b2,
     const float* __restrict__ s2, const float* __restrict__ t2,
     float* __restrict__ out){
  const int tid  = threadIdx.x;
  const int lane = tid & 63;
  const size_t e = (size_t)blockIdx.x*256 + tid;
  const int b = (int)(e >> 16);
  const int n = (int)((e >> 4) & 4095);
  const float rx = rel[e*3+0], ry = rel[e*3+1], rz = rel[e*3+2];
  float h1[64];
  #pragma unroll
  for (int o=0;o<64;o++){
    float g = fmaf(w1[o*3+0], rx, fmaf(w1[o*3+1], ry, fmaf(w1[o*3+2], rz, b1[o])));
    h1[o] = fmaxf(fmaf(g, s1[o], t1[o]), 0.0f);
  }
  float h2[64];
  for (int o=0;o<64;o++){
    const float* __restrict__ row = w2 + o*64;
    float a0=0,a1=0,a2=0,a3=0;
    #pragma unroll
    for (int c=0;c<64;c+=4){
      a0 = fmaf(row[c+0], h1[c+0], a0);
      a1 = fmaf(row[c+1], h1[c+1], a1);
      a2 = fmaf(row[c+2], h1[c+2], a2);
      a3 = fmaf(row[c+3], h1[c+3], a3);
    }
    float g2 = ((a0+a1)+(a2+a3)) + b2[o];
    h2[o] = fmaxf(fmaf(g2, s2[o], t2[o]), 0.0f);
  }
  for (int o=0;o<64;o++){
    const float* __restrict__ row = w2 + o*64;
    float a0=0,a1=0,a2=0,a3=0;
    #pragma unroll
    for (int c=0;c<64;c+=4){
      a0 = fmaf(row[c+0], h2[c+0], a0);
      a1 = fmaf(row[c+1], h2[c+1], a1);
      a2 = fmaf(row[c+2], h2[c+2], a2);
      a3 = fmaf(row[c+3], h2[c+3], a3);
    }
    float g3 = ((a0+a1)+(a2+a3)) + b2[o];
    g3 = fmaxf(g3, __shfl_xor(g3, 1));
    g3 = fmaxf(g3, __shfl_xor(g3, 2));
    g3 = fmaxf(g3, __shfl_xor(g3, 4));
    g3 = fmaxf(g3, __shfl_xor(g3, 8));
    if ((lane & 15) == 0){
      out[(((size_t)b*64 + o) << 12) + n] = g3;
    }
  }
}

extern "C" void kernel_launch(void* const* d_in, const int* in_sizes, int n_in,
                              void* d_out, int out_size, void* d_ws, size_t ws_size,
                              hipStream_t stream){
  const float* xyz   = (const float*)d_in[0];
  const float* w1    = (const float*)d_in[1];
  const float* b1    = (const float*)d_in[2];
  const float* w2    = (const float*)d_in[3];
  const float* b2    = (const float*)d_in[4];
  const float* gamma = (const float*)d_in[5];
  const float* beta  = (const float*)d_in[6];
  float* out = (float*)d_out;
  float* ws  = (float*)d_ws;

  float*  rel  = ws + REL_OFF;
  float4* pts4 = (float4*)(ws + PTS4_OFF);
  float*  mom  = ws + ACC_OFF;        // 9 used (padded to 16)
  float*  gsum = mom + 16;            // 64
  float*  gsq  = mom + 80;            // 64
  float*  s1   = ws + 1704080;
  float*  t1   = ws + 1704144;
  float*  s2   = ws + 1704208;
  float*  t2   = ws + 1704272;

  hipMemsetAsync(mom, 0, 144*sizeof(float), stream);
  prep_kernel  <<<128,  256, 0, stream>>>(xyz, pts4);
  knn_kernel   <<<512,  512, 0, stream>>>(pts4, rel, mom);
  stats1_kernel<<<1,     64, 0, stream>>>(mom, w1, b1, gamma, beta, s1, t1);
  pass2_kernel <<<2048, 256, 0, stream>>>(rel, w1, b1, s1, t1, w2, b2, gsum, gsq);
  stats2_kernel<<<1,     64, 0, stream>>>(gsum, gsq, gamma, beta, s2, t2);
  pass3_kernel <<<2048, 256, 0, stream>>>(rel, w1, b1, s1, t1, w2, b2, s2, t2, out);
}

// Round 5
// 481.935 us; speedup vs baseline: 1.7067x; 1.4542x over previous
//
#include <hip/hip_runtime.h>

typedef unsigned int u32;
typedef unsigned short u16;
typedef unsigned long long u64;
typedef __attribute__((ext_vector_type(8))) short bf16x8;
typedef __attribute__((ext_vector_type(4))) float f32x4;

// ---------------- workspace layout (floats) ----------------
#define REL_OFF   0
#define PTS4_OFF  1572864
#define ACC_OFF   1703936   // mom[16] | gsum8[512] | gsq8[512]  (1040 zeroed)
#define A1_OFF    1704976   // folded layer1 consts: [ch]{ax,ay,az,c} = 256 floats
#define S2_OFF    1705232   // 64
#define C2_OFF    1705296   // 64

__device__ __forceinline__ u32 bfh(float v){           // RNE bf16 hi bits
  u32 x = __float_as_uint(v);
  return (x + 0x7FFFu + ((x >> 16) & 1u)) >> 16;
}
__device__ __forceinline__ void split2(float v, u16* hh, u16* hl){
  u32 h = bfh(v);
  float hif = __uint_as_float(h << 16);
  u32 l = bfh(v - hif);
  *hh = (u16)h; *hl = (u16)l;
}

__global__ __launch_bounds__(256) void prep_kernel(const float* __restrict__ xyz,
                                                   float4* __restrict__ pts4){
#pragma clang fp contract(off)
  int g = blockIdx.x*256 + threadIdx.x;
  int b = g >> 12, n = g & 4095;
  const float* xb = xyz + (size_t)b*12288;
  float x = xb[n], y = xb[4096+n], z = xb[8192+n];
  float sq = (x*x + y*y) + z*z;
  pts4[g] = make_float4(x,y,z,sq);
}

// 48-bit key = (order-mapped f32 dist << 16) | u16(4095 - j): descending value,
// ties -> lower index first (jax top_k order). Insert of 0 is a provable no-op.
__device__ __forceinline__ void chain_insert(u64* s, u64 key){
  #pragma unroll
  for (int t=0;t<17;t++){
    bool gt = key > s[t];
    u64 mx = gt ? key : s[t];
    key = gt ? s[t] : key;
    s[t] = mx;
  }
}

// UNCHANGED from round 4 (283 us): per-lane top-17, block-shared gate.
__global__ __launch_bounds__(512, 2) void knn_kernel(const float4* __restrict__ pts4,
                                                     float* __restrict__ rel,
                                                     float* __restrict__ mom){
#pragma clang fp contract(off)
  __shared__ u32 lA[8840];
  __shared__ u16 lB[8840];
  __shared__ float bmom[16];
  __shared__ u32 gate[64];
  const int tid  = threadIdx.x;
  const int lane = tid & 63;
  const int wave = tid >> 6;
  const int blk  = blockIdx.x;
  const int b    = blk >> 6;
  const int q0   = (blk & 63) << 6;
  const float4* __restrict__ P = pts4 + ((size_t)b << 12);
  const float4 me = P[q0 + lane];
  if (tid < 16) bmom[tid] = 0.0f;
  if (tid < 64) gate[tid] = 0u;
  __syncthreads();

  u64 s[17];
  #pragma unroll
  for (int i=0;i<17;i++) s[i] = 0ull;
  u32 kminhi = 0u;
  int cnt = 0;
  const int base = tid*17;
  const int j0 = __builtin_amdgcn_readfirstlane(wave << 9);

  for (int g8 = 0; g8 < 512; g8 += 8){
    kminhi = max(kminhi, gate[lane]);
    float4 c[8];
    #pragma unroll
    for (int u=0;u<8;u++) c[u] = P[j0 + g8 + u];
    #pragma unroll
    for (int u=0;u<8;u++){
      const int j = j0 + g8 + u;
      float dot = (me.x*c[u].x + me.y*c[u].y) + me.z*c[u].z;
      float d   = (me.w + c[u].w) - 2.0f*dot;
      u32 ub = __float_as_uint(d);
      ub ^= ((u32)(((int)ub) >> 31) | 0x80000000u);
      if (ub >= kminhi){
        lA[base+cnt] = ub;
        lB[base+cnt] = (u16)(4095 - j);
        cnt++;
      }
    }
    if (__any(cnt >= 9)){
      int i = 0;
      while (__any(i < cnt)){
        u32 a = lA[base+i];
        u16 v = lB[base+i];
        u64 key = (i < cnt) ? (((u64)a << 16) | v) : 0ull;
        chain_insert(s, key);
        i++;
      }
      cnt = 0;
      u32 own = (u32)(s[16] >> 16);
      if (own) atomicMax(&gate[lane], own);
      kminhi = max(kminhi, own);
    }
  }
  {
    int i = 0;
    while (__any(i < cnt)){
      u32 a = lA[base+i];
      u16 v = lB[base+i];
      u64 key = (i < cnt) ? (((u64)a << 16) | v) : 0ull;
      chain_insert(s, key);
      i++;
    }
  }
  __syncthreads();
  #pragma unroll
  for (int i=0;i<17;i++){
    const int o = (wave*17 + i)*65 + lane;
    lA[o] = (u32)(s[i] >> 16);
    lB[o] = (u16)s[i];
  }
  __syncthreads();

  {
    const int q   = tid >> 3;
    const int sub = tid & 7;
    const float4 qp = P[q0 + q];
    float* __restrict__ ro = rel + (size_t)((b << 12) + q0 + q) * 48;
    float sm0=0,sm1=0,sm2=0,sm3=0,sm4=0,sm5=0,sm6=0,sm7=0,sm8=0;
    int p = 0;
    for (int r=0;r<17;r++){
      const int idx = (sub*17 + p)*65 + q;
      u64 mine = ((u64)lA[idx] << 16) | lB[idx];
      u64 kmax = mine;
      #pragma unroll
      for (int off=1; off<8; off<<=1){
        u64 o2 = __shfl_xor(kmax, off);
        kmax = (o2 > kmax) ? o2 : kmax;
      }
      p += (mine == kmax);
      if (r > 0 && sub == 0){
        const int j = 4095 - (int)(u32)(kmax & 0xFFFFull);
        const float4 nb = P[j];
        const float rx = nb.x - qp.x;
        const float ry = nb.y - qp.y;
        const float rz = nb.z - qp.z;
        ro[(r-1)*3+0] = rx; ro[(r-1)*3+1] = ry; ro[(r-1)*3+2] = rz;
        sm0 += rx; sm1 += ry; sm2 += rz;
        sm3 += rx*rx; sm4 += rx*ry; sm5 += rx*rz;
        sm6 += ry*ry; sm7 += ry*rz; sm8 += rz*rz;
      }
    }
    #pragma unroll
    for (int off=8; off<64; off<<=1){
      sm0 += __shfl_xor(sm0, off); sm1 += __shfl_xor(sm1, off); sm2 += __shfl_xor(sm2, off);
      sm3 += __shfl_xor(sm3, off); sm4 += __shfl_xor(sm4, off); sm5 += __shfl_xor(sm5, off);
      sm6 += __shfl_xor(sm6, off); sm7 += __shfl_xor(sm7, off); sm8 += __shfl_xor(sm8, off);
    }
    if (lane == 0){
      atomicAdd(&bmom[0], sm0); atomicAdd(&bmom[1], sm1); atomicAdd(&bmom[2], sm2);
      atomicAdd(&bmom[3], sm3); atomicAdd(&bmom[4], sm4); atomicAdd(&bmom[5], sm5);
      atomicAdd(&bmom[6], sm6); atomicAdd(&bmom[7], sm7); atomicAdd(&bmom[8], sm8);
    }
  }
  __syncthreads();
  if (tid < 9) atomicAdd(&mom[tid], bmom[tid]);
}

// BN1 analytic from rel moments; writes FOLDED layer1 consts a1[ch] = {s1*w1, s1*b1+t1}.
__global__ void stats1_kernel(const float* __restrict__ mom,
                              const float* __restrict__ w1, const float* __restrict__ b1,
                              const float* __restrict__ gamma, const float* __restrict__ beta,
                              float* __restrict__ a1){
  const int o = threadIdx.x;           // 64 threads
  const float Minv = 1.0f / 524288.0f;
  float m0 = mom[0]*Minv, m1 = mom[1]*Minv, m2 = mom[2]*Minv;
  float cxx = mom[3]*Minv - m0*m0;
  float cxy = mom[4]*Minv - m0*m1;
  float cxz = mom[5]*Minv - m0*m2;
  float cyy = mom[6]*Minv - m1*m1;
  float cyz = mom[7]*Minv - m1*m2;
  float czz = mom[8]*Minv - m2*m2;
  float wx = w1[o*3+0], wy = w1[o*3+1], wz = w1[o*3+2];
  float mu  = wx*m0 + wy*m1 + wz*m2 + b1[o];
  float var = wx*wx*cxx + wy*wy*cyy + wz*wz*czz
            + 2.0f*(wx*wy*cxy + wx*wz*cxz + wy*wz*cyz);
  float istd = rsqrtf(var + 1e-5f);
  float sc = gamma[o]*istd;
  float t1 = beta[o] - mu*sc;
  a1[o*4+0] = wx*sc;
  a1[o*4+1] = wy*sc;
  a1[o*4+2] = wz*sc;
  a1[o*4+3] = fmaf(sc, b1[o], t1);
}

// ---- shared MFMA staging: W2 split (64x64 -> LDS stride 72) + H1 built from rel ----
__device__ __forceinline__ void stage_WH(int tid, int blk,
    const float* __restrict__ rel, const float* __restrict__ a1,
    const float* __restrict__ w2,
    u16* Wh, u16* Wl, u16* Hh, u16* Hl){
  {
    int base = tid*16;
    #pragma unroll
    for (int i=0;i<16;i++){
      int idx = base+i; int r = idx>>6, c = idx&63;
      split2(w2[idx], &Wh[r*72+c], &Wl[r*72+c]);
    }
  }
  {
    int e = tid>>1, half = tid&1;            // pair-split to spread LDS banks
    size_t eg = (size_t)blk*128 + e;
    float rx = rel[eg*3+0], ry = rel[eg*3+1], rz = rel[eg*3+2];
    const float4* A1 = (const float4*)a1;
    #pragma unroll
    for (int i=0;i<32;i++){
      int ch = half*32 + i;
      float4 a = A1[ch];
      float g = fmaf(a.x, rx, fmaf(a.y, ry, fmaf(a.z, rz, a.w)));
      g = fmaxf(g, 0.0f);
      split2(g, &Hh[e*72+ch], &Hl[e*72+ch]);
    }
  }
}

#define MFMA6(dst, b_h0, b_h1, b_l0, b_l1)                                   \
  dst = __builtin_amdgcn_mfma_f32_16x16x32_bf16(aH0, b_h0, dst, 0,0,0);      \
  dst = __builtin_amdgcn_mfma_f32_16x16x32_bf16(aH1, b_h1, dst, 0,0,0);      \
  dst = __builtin_amdgcn_mfma_f32_16x16x32_bf16(aH0, b_l0, dst, 0,0,0);      \
  dst = __builtin_amdgcn_mfma_f32_16x16x32_bf16(aH1, b_l1, dst, 0,0,0);      \
  dst = __builtin_amdgcn_mfma_f32_16x16x32_bf16(aL0, b_h0, dst, 0,0,0);      \
  dst = __builtin_amdgcn_mfma_f32_16x16x32_bf16(aL1, b_h1, dst, 0,0,0);

// Pass 2 (MFMA): g2 = W2@H1 + b2; accumulate per-channel sum/sumsq into
// 8-way-striped global accumulators (contention /8).
__global__ __launch_bounds__(256, 2) void pass2_mfma(
    const float* __restrict__ rel, const float* __restrict__ a1,
    const float* __restrict__ w2, const float* __restrict__ b2,
    float* __restrict__ gsum8, float* __restrict__ gsq8){
  __shared__ alignas(16) u16 Wh[64*72], Wl[64*72];
  __shared__ alignas(16) u16 Hh[128*72], Hl[128*72];
  const int tid = threadIdx.x, blk = blockIdx.x;
  stage_WH(tid, blk, rel, a1, w2, Wh, Wl, Hh, Hl);
  __syncthreads();
  const int lane = tid & 63, wave = tid >> 6;
  const int col = lane & 15, quad = lane >> 4;
  const int offA = (wave*16 + col)*72 + quad*8;
  bf16x8 aH0 = *(const bf16x8*)&Wh[offA];
  bf16x8 aH1 = *(const bf16x8*)&Wh[offA+32];
  bf16x8 aL0 = *(const bf16x8*)&Wl[offA];
  bf16x8 aL1 = *(const bf16x8*)&Wl[offA+32];
  float b2v[4];
  #pragma unroll
  for (int r=0;r<4;r++) b2v[r] = b2[wave*16 + quad*4 + r];
  float ssum[4] = {0,0,0,0}, ssq[4] = {0,0,0,0};
  #pragma unroll
  for (int nt=0; nt<8; nt++){
    const int offB = (nt*16 + col)*72 + quad*8;
    bf16x8 bH0 = *(const bf16x8*)&Hh[offB];
    bf16x8 bH1 = *(const bf16x8*)&Hh[offB+32];
    bf16x8 bL0 = *(const bf16x8*)&Hl[offB];
    bf16x8 bL1 = *(const bf16x8*)&Hl[offB+32];
    f32x4 a = {0.f,0.f,0.f,0.f};
    MFMA6(a, bH0, bH1, bL0, bL1)
    #pragma unroll
    for (int r=0;r<4;r++){
      float t = a[r] + b2v[r];
      ssum[r] += t; ssq[r] += t*t;
    }
  }
  #pragma unroll
  for (int off=1; off<16; off<<=1){
    #pragma unroll
    for (int r=0;r<4;r++){
      ssum[r] += __shfl_xor(ssum[r], off);
      ssq[r]  += __shfl_xor(ssq[r],  off);
    }
  }
  if (col == 0){
    const int st = (blk & 7)*64;
    #pragma unroll
    for (int r=0;r<4;r++){
      int ch = wave*16 + quad*4 + r;
      atomicAdd(&gsum8[st+ch], ssum[r]);
      atomicAdd(&gsq8[st+ch],  ssq[r]);
    }
  }
}

// BN2 consts from striped sums: s2 = gamma*istd, c2 = s2*b2 + (beta - mu*s2).
__global__ void stats2_kernel(const float* __restrict__ gsum8, const float* __restrict__ gsq8,
                              const float* __restrict__ b2,
                              const float* __restrict__ gamma, const float* __restrict__ beta,
                              float* __restrict__ s2a, float* __restrict__ c2a){
  const int o = threadIdx.x;
  float s = 0.f, q = 0.f;
  #pragma unroll
  for (int i=0;i<8;i++){ s += gsum8[i*64+o]; q += gsq8[i*64+o]; }
  const float Minv = 1.0f / 524288.0f;
  float mu  = s*Minv;
  float var = q*Minv - mu*mu;
  float istd = rsqrtf(var + 1e-5f);
  float sc = gamma[o]*istd;
  float t2 = beta[o] - mu*sc;
  s2a[o] = sc;
  c2a[o] = fmaf(sc, b2[o], t2);
}

// Pass 3 (MFMA): H1 -> g2 -> (BN2+relu) H2 (overwrites H1 in LDS) -> g3 -> max over k.
__global__ __launch_bounds__(256, 2) void pass3_mfma(
    const float* __restrict__ rel, const float* __restrict__ a1,
    const float* __restrict__ w2, const float* __restrict__ b2,
    const float* __restrict__ s2a, const float* __restrict__ c2a,
    float* __restrict__ out){
  __shared__ alignas(16) u16 Wh[64*72], Wl[64*72];
  __shared__ alignas(16) u16 Hh[128*72], Hl[128*72];
  const int tid = threadIdx.x, blk = blockIdx.x;
  stage_WH(tid, blk, rel, a1, w2, Wh, Wl, Hh, Hl);
  __syncthreads();
  const int lane = tid & 63, wave = tid >> 6;
  const int col = lane & 15, quad = lane >> 4;
  const int offA = (wave*16 + col)*72 + quad*8;
  bf16x8 aH0 = *(const bf16x8*)&Wh[offA];
  bf16x8 aH1 = *(const bf16x8*)&Wh[offA+32];
  bf16x8 aL0 = *(const bf16x8*)&Wl[offA];
  bf16x8 aL1 = *(const bf16x8*)&Wl[offA+32];
  float s2v[4], c2v[4], b2v[4];
  #pragma unroll
  for (int r=0;r<4;r++){
    int ch = wave*16 + quad*4 + r;
    s2v[r] = s2a[ch]; c2v[r] = c2a[ch]; b2v[r] = b2[ch];
  }
  f32x4 acc[8];
  #pragma unroll
  for (int nt=0; nt<8; nt++){
    const int offB = (nt*16 + col)*72 + quad*8;
    bf16x8 bH0 = *(const bf16x8*)&Hh[offB];
    bf16x8 bH1 = *(const bf16x8*)&Hh[offB+32];
    bf16x8 bL0 = *(const bf16x8*)&Hl[offB];
    bf16x8 bL1 = *(const bf16x8*)&Hl[offB+32];
    f32x4 a = {0.f,0.f,0.f,0.f};
    MFMA6(a, bH0, bH1, bL0, bL1)
    acc[nt] = a;
  }
  __syncthreads();   // all layer-2 H reads done -> safe to overwrite with H2
  #pragma unroll
  for (int nt=0; nt<8; nt++){
    const int e = nt*16 + col;
    const int ch0 = wave*16 + quad*4;
    u64 ph = 0, pl = 0;
    #pragma unroll
    for (int r=0;r<4;r++){
      float g = acc[nt][r] + b2v[r];
      float h = fmaxf(fmaf(g, s2v[r], c2v[r]), 0.0f);
      u32 hb = bfh(h);
      u32 lb = bfh(h - __uint_as_float(hb << 16));
      ph |= ((u64)hb) << (16*r);
      pl |= ((u64)lb) << (16*r);
    }
    *(u64*)&Hh[e*72 + ch0] = ph;
    *(u64*)&Hl[e*72 + ch0] = pl;
  }
  __syncthreads();
  #pragma unroll
  for (int nt=0; nt<8; nt++){
    const int offB = (nt*16 + col)*72 + quad*8;
    bf16x8 bH0 = *(const bf16x8*)&Hh[offB];
    bf16x8 bH1 = *(const bf16x8*)&Hh[offB+32];
    bf16x8 bL0 = *(const bf16x8*)&Hl[offB];
    bf16x8 bL1 = *(const bf16x8*)&Hl[offB+32];
    f32x4 a = {0.f,0.f,0.f,0.f};
    MFMA6(a, bH0, bH1, bL0, bL1)
    float m0 = a[0]+b2v[0], m1 = a[1]+b2v[1], m2 = a[2]+b2v[2], m3 = a[3]+b2v[3];
    #pragma unroll
    for (int off=1; off<16; off<<=1){
      m0 = fmaxf(m0, __shfl_xor(m0, off));
      m1 = fmaxf(m1, __shfl_xor(m1, off));
      m2 = fmaxf(m2, __shfl_xor(m2, off));
      m3 = fmaxf(m3, __shfl_xor(m3, off));
    }
    if (col == 0){
      const int gp = blk*8 + nt;
      const int b = gp >> 12, n = gp & 4095;
      const int ch0 = wave*16 + quad*4;
      size_t o0 = (((size_t)b*64 + ch0) << 12) + n;
      out[o0]         = m0;
      out[o0 + 4096]  = m1;
      out[o0 + 8192]  = m2;
      out[o0 + 12288] = m3;
    }
  }
}

extern "C" void kernel_launch(void* const* d_in, const int* in_sizes, int n_in,
                              void* d_out, int out_size, void* d_ws, size_t ws_size,
                              hipStream_t stream){
  const float* xyz   = (const float*)d_in[0];
  const float* w1    = (const float*)d_in[1];
  const float* b1    = (const float*)d_in[2];
  const float* w2    = (const float*)d_in[3];
  const float* b2    = (const float*)d_in[4];
  const float* gamma = (const float*)d_in[5];
  const float* beta  = (const float*)d_in[6];
  float* out = (float*)d_out;
  float* ws  = (float*)d_ws;

  float*  rel   = ws + REL_OFF;
  float4* pts4  = (float4*)(ws + PTS4_OFF);
  float*  mom   = ws + ACC_OFF;        // 16
  float*  gsum8 = mom + 16;            // 512
  float*  gsq8  = mom + 528;           // 512
  float*  a1    = ws + A1_OFF;         // 256
  float*  s2a   = ws + S2_OFF;         // 64
  float*  c2a   = ws + C2_OFF;         // 64

  hipMemsetAsync(mom, 0, 1040*sizeof(float), stream);
  prep_kernel  <<<128,  256, 0, stream>>>(xyz, pts4);
  knn_kernel   <<<512,  512, 0, stream>>>(pts4, rel, mom);
  stats1_kernel<<<1,     64, 0, stream>>>(mom, w1, b1, gamma, beta, a1);
  pass2_mfma   <<<4096, 256, 0, stream>>>(rel, a1, w2, b2, gsum8, gsq8);
  stats2_kernel<<<1,     64, 0, stream>>>(gsum8, gsq8, b2, gamma, beta, s2a, c2a);
  pass3_mfma   <<<4096, 256, 0, stream>>>(rel, a1, w2, b2, s2a, c2a, out);
}

// Round 6
// 453.089 us; speedup vs baseline: 1.8153x; 1.0637x over previous
//
#include <hip/hip_runtime.h>

typedef unsigned int u32;
typedef unsigned short u16;
typedef unsigned long long u64;
typedef __attribute__((ext_vector_type(8))) short bf16x8;
typedef __attribute__((ext_vector_type(4))) float f32x4;

// ---------------- workspace layout (floats) ----------------
#define REL_OFF   0
#define PTS4_OFF  1572864
#define ACC_OFF   1703936   // mom[16] | gsum8[512] | gsq8[512]  (1040 zeroed)
#define A1_OFF    1704976   // folded layer1 consts: [ch]{ax,ay,az,c} = 256 floats
#define S2_OFF    1705232   // 64
#define C2_OFF    1705296   // 64

__device__ __forceinline__ u32 bfh(float v){           // RNE bf16 hi bits
  u32 x = __float_as_uint(v);
  return (x + 0x7FFFu + ((x >> 16) & 1u)) >> 16;
}
__device__ __forceinline__ void split2(float v, u16* hh, u16* hl){
  u32 h = bfh(v);
  float hif = __uint_as_float(h << 16);
  u32 l = bfh(v - hif);
  *hh = (u16)h; *hl = (u16)l;
}

__global__ __launch_bounds__(256) void prep_kernel(const float* __restrict__ xyz,
                                                   float4* __restrict__ pts4){
#pragma clang fp contract(off)
  int g = blockIdx.x*256 + threadIdx.x;
  int b = g >> 12, n = g & 4095;
  const float* xb = xyz + (size_t)b*12288;
  float x = xb[n], y = xb[4096+n], z = xb[8192+n];
  float sq = (x*x + y*y) + z*z;
  pts4[g] = make_float4(x,y,z,sq);
}

// 48-bit key = (order-mapped f32 dist << 16) | u16(4095 - j): descending value,
// ties -> lower index first (jax top_k order). Insert of 0 is a provable no-op.
__device__ __forceinline__ void chain_insert(u64* s, u64 key){
  #pragma unroll
  for (int t=0;t<17;t++){
    bool gt = key > s[t];
    u64 mx = gt ? key : s[t];
    key = gt ? s[t] : key;
    s[t] = mx;
  }
}

// KNN: one block = 64 queries of one batch; 8 waves; wave w scans candidates
// [w*512, w*512+512). ROUND-6 restructure: per-lane 16-slot ring buffer in LDS
// (stride 17: odd -> conflict-free) drained at ONE masked chain-insert per
// 8-candidate group (insert of key=0 is a no-op), replacing wave-synchronized
// batch compaction whose cost was Sum_events max_lane(cnt) ~ 300-470 inserts
// per wave (R5 counters: ~57k VALU instr/wave). Warm-up: first 24 candidates
// inserted directly (fills depth-17 chain -> s[16] sound gate immediately).
// Gate = block-shared LDS atomicMax of each wave's local 17th (monotone ->
// stale reads conservative). Merge phase unchanged from R4.
__global__ __launch_bounds__(512, 2) void knn_kernel(const float4* __restrict__ pts4,
                                                     float* __restrict__ rel,
                                                     float* __restrict__ mom){
#pragma clang fp contract(off)
  __shared__ u32 lA[8840];   // phase1: ring [tid*17 + (wr&15)] ; phase2: [(w*17+i)*65+q]=key hi32
  __shared__ u16 lB[8840];   // phase1: u16(4095-j)             ; phase2: key lo16
  __shared__ float bmom[16];
  __shared__ u32 gate[64];   // per-query shared lower bound on global-17th dist bits
  const int tid  = threadIdx.x;
  const int lane = tid & 63;
  const int wave = tid >> 6;
  const int blk  = blockIdx.x;
  const int b    = blk >> 6;
  const int q0   = (blk & 63) << 6;
  const float4* __restrict__ P = pts4 + ((size_t)b << 12);
  const float4 me = P[q0 + lane];
  if (tid < 16) bmom[tid] = 0.0f;
  if (tid < 64) gate[tid] = 0u;
  __syncthreads();

  u64 s[17];
  #pragma unroll
  for (int i=0;i<17;i++) s[i] = 0ull;
  const int base = tid*17;
  const int j0 = __builtin_amdgcn_readfirstlane(wave << 9);
  u32 wr = 0, rd = 0;

  // ---- warm-up: first 24 candidates inserted directly (no gate, no buffer) ----
  for (int g8 = 0; g8 < 24; g8 += 8){
    float4 c[8];
    #pragma unroll
    for (int u=0;u<8;u++) c[u] = P[j0 + g8 + u];   // wave-uniform -> s_load
    #pragma unroll
    for (int u=0;u<8;u++){
      const int j = j0 + g8 + u;
      float dot = (me.x*c[u].x + me.y*c[u].y) + me.z*c[u].z;
      float d   = (me.w + c[u].w) - 2.0f*dot;
      u32 ub = __float_as_uint(d);
      ub ^= ((u32)(((int)ub) >> 31) | 0x80000000u);
      chain_insert(s, ((u64)ub << 16) | (u16)(4095 - j));
    }
  }
  atomicMax(&gate[lane], (u32)(s[16] >> 16));

  // one masked drain step: pop FIFO item (if any) into the chain
  #define INSERT_STEP() {                                        \
    bool act = rd != wr;                                         \
    int pos = base + (int)(rd & 15u);                            \
    u32 a_ = lA[pos]; u16 v_ = lB[pos];                          \
    u64 key = act ? (((u64)a_ << 16) | v_) : 0ull;               \
    if (__any(key > s[16])) chain_insert(s, key);                \
    rd += act;                                                   \
  }

  for (int g8 = 24; g8 < 512; g8 += 8){
    // room guard: ensure >= 8 free slots (rarely fires after warm-up)
    while (__any((int)(wr - rd) > 8)) INSERT_STEP();
    float4 c[8];
    #pragma unroll
    for (int u=0;u<8;u++) c[u] = P[j0 + g8 + u];   // wave-uniform -> s_load
    INSERT_STEP();                                  // overlap chain with s_load latency
    u32 kmin = max(gate[lane], (u32)(s[16] >> 16));
    #pragma unroll
    for (int u=0;u<8;u++){
      const int j = j0 + g8 + u;
      float dot = (me.x*c[u].x + me.y*c[u].y) + me.z*c[u].z;
      float d   = (me.w + c[u].w) - 2.0f*dot;
      u32 ub = __float_as_uint(d);
      ub ^= ((u32)(((int)ub) >> 31) | 0x80000000u);
      if (ub >= kmin){                              // conservative gate (>= keeps ties)
        lA[base + (int)(wr & 15u)] = ub;
        lB[base + (int)(wr & 15u)] = (u16)(4095 - j);
        wr++;
      }
    }
    if (((g8 >> 3) & 3) == 3){                      // publish every 4th group
      u32 own = (u32)(s[16] >> 16);
      if (own) atomicMax(&gate[lane], own);
    }
  }
  while (__any(rd != wr)) INSERT_STEP();            // final drain
  #undef INSERT_STEP

  __syncthreads();                    // buffers dead; reuse LDS for sorted lists
  #pragma unroll
  for (int i=0;i<17;i++){
    const int o = (wave*17 + i)*65 + lane;
    lA[o] = (u32)(s[i] >> 16);
    lB[o] = (u16)s[i];
  }
  __syncthreads();

  // 8-way merge, 8 lanes per query (all 512 threads active).
  // Lists are disjoint candidate ranges -> keys unique, butterfly-max is exact.
  {
    const int q   = tid >> 3;
    const int sub = tid & 7;
    const float4 qp = P[q0 + q];
    float* __restrict__ ro = rel + (size_t)((b << 12) + q0 + q) * 48;
    float sm0=0,sm1=0,sm2=0,sm3=0,sm4=0,sm5=0,sm6=0,sm7=0,sm8=0;
    int p = 0;
    for (int r=0;r<17;r++){
      const int idx = (sub*17 + p)*65 + q;
      u64 mine = ((u64)lA[idx] << 16) | lB[idx];
      u64 kmax = mine;
      #pragma unroll
      for (int off=1; off<8; off<<=1){
        u64 o2 = __shfl_xor(kmax, off);
        kmax = (o2 > kmax) ? o2 : kmax;
      }
      p += (mine == kmax);
      if (r > 0 && sub == 0){   // drop rank 0 (the single farthest), keep 1..16
        const int j = 4095 - (int)(u32)(kmax & 0xFFFFull);
        const float4 nb = P[j];
        const float rx = nb.x - qp.x;
        const float ry = nb.y - qp.y;
        const float rz = nb.z - qp.z;
        ro[(r-1)*3+0] = rx; ro[(r-1)*3+1] = ry; ro[(r-1)*3+2] = rz;
        sm0 += rx; sm1 += ry; sm2 += rz;
        sm3 += rx*rx; sm4 += rx*ry; sm5 += rx*rz;
        sm6 += ry*ry; sm7 += ry*rz; sm8 += rz*rz;
      }
    }
    #pragma unroll
    for (int off=8; off<64; off<<=1){
      sm0 += __shfl_xor(sm0, off); sm1 += __shfl_xor(sm1, off); sm2 += __shfl_xor(sm2, off);
      sm3 += __shfl_xor(sm3, off); sm4 += __shfl_xor(sm4, off); sm5 += __shfl_xor(sm5, off);
      sm6 += __shfl_xor(sm6, off); sm7 += __shfl_xor(sm7, off); sm8 += __shfl_xor(sm8, off);
    }
    if (lane == 0){
      atomicAdd(&bmom[0], sm0); atomicAdd(&bmom[1], sm1); atomicAdd(&bmom[2], sm2);
      atomicAdd(&bmom[3], sm3); atomicAdd(&bmom[4], sm4); atomicAdd(&bmom[5], sm5);
      atomicAdd(&bmom[6], sm6); atomicAdd(&bmom[7], sm7); atomicAdd(&bmom[8], sm8);
    }
  }
  __syncthreads();
  if (tid < 9) atomicAdd(&mom[tid], bmom[tid]);
}

// BN1 analytic from rel moments; writes FOLDED layer1 consts a1[ch] = {s1*w1, s1*b1+t1}.
__global__ void stats1_kernel(const float* __restrict__ mom,
                              const float* __restrict__ w1, const float* __restrict__ b1,
                              const float* __restrict__ gamma, const float* __restrict__ beta,
                              float* __restrict__ a1){
  const int o = threadIdx.x;           // 64 threads
  const float Minv = 1.0f / 524288.0f;
  float m0 = mom[0]*Minv, m1 = mom[1]*Minv, m2 = mom[2]*Minv;
  float cxx = mom[3]*Minv - m0*m0;
  float cxy = mom[4]*Minv - m0*m1;
  float cxz = mom[5]*Minv - m0*m2;
  float cyy = mom[6]*Minv - m1*m1;
  float cyz = mom[7]*Minv - m1*m2;
  float czz = mom[8]*Minv - m2*m2;
  float wx = w1[o*3+0], wy = w1[o*3+1], wz = w1[o*3+2];
  float mu  = wx*m0 + wy*m1 + wz*m2 + b1[o];
  float var = wx*wx*cxx + wy*wy*cyy + wz*wz*czz
            + 2.0f*(wx*wy*cxy + wx*wz*cxz + wy*wz*cyz);
  float istd = rsqrtf(var + 1e-5f);
  float sc = gamma[o]*istd;
  float t1 = beta[o] - mu*sc;
  a1[o*4+0] = wx*sc;
  a1[o*4+1] = wy*sc;
  a1[o*4+2] = wz*sc;
  a1[o*4+3] = fmaf(sc, b1[o], t1);
}

// ---- shared MFMA staging: W2 split (64x64 -> LDS stride 72) + H1 built from rel ----
__device__ __forceinline__ void stage_WH(int tid, int blk,
    const float* __restrict__ rel, const float* __restrict__ a1,
    const float* __restrict__ w2,
    u16* Wh, u16* Wl, u16* Hh, u16* Hl){
  {
    int base = tid*16;
    #pragma unroll
    for (int i=0;i<16;i++){
      int idx = base+i; int r = idx>>6, c = idx&63;
      split2(w2[idx], &Wh[r*72+c], &Wl[r*72+c]);
    }
  }
  {
    int e = tid>>1, half = tid&1;            // pair-split to spread LDS banks
    size_t eg = (size_t)blk*128 + e;
    float rx = rel[eg*3+0], ry = rel[eg*3+1], rz = rel[eg*3+2];
    const float4* A1 = (const float4*)a1;
    #pragma unroll
    for (int i=0;i<32;i++){
      int ch = half*32 + i;
      float4 a = A1[ch];
      float g = fmaf(a.x, rx, fmaf(a.y, ry, fmaf(a.z, rz, a.w)));
      g = fmaxf(g, 0.0f);
      split2(g, &Hh[e*72+ch], &Hl[e*72+ch]);
    }
  }
}

#define MFMA6(dst, b_h0, b_h1, b_l0, b_l1)                                   \
  dst = __builtin_amdgcn_mfma_f32_16x16x32_bf16(aH0, b_h0, dst, 0,0,0);      \
  dst = __builtin_amdgcn_mfma_f32_16x16x32_bf16(aH1, b_h1, dst, 0,0,0);      \
  dst = __builtin_amdgcn_mfma_f32_16x16x32_bf16(aH0, b_l0, dst, 0,0,0);      \
  dst = __builtin_amdgcn_mfma_f32_16x16x32_bf16(aH1, b_l1, dst, 0,0,0);      \
  dst = __builtin_amdgcn_mfma_f32_16x16x32_bf16(aL0, b_h0, dst, 0,0,0);      \
  dst = __builtin_amdgcn_mfma_f32_16x16x32_bf16(aL1, b_h1, dst, 0,0,0);

// Pass 2 (MFMA): g2 = W2@H1 + b2; accumulate per-channel sum/sumsq into
// 8-way-striped global accumulators (contention /8).
__global__ __launch_bounds__(256, 2) void pass2_mfma(
    const float* __restrict__ rel, const float* __restrict__ a1,
    const float* __restrict__ w2, const float* __restrict__ b2,
    float* __restrict__ gsum8, float* __restrict__ gsq8){
  __shared__ alignas(16) u16 Wh[64*72], Wl[64*72];
  __shared__ alignas(16) u16 Hh[128*72], Hl[128*72];
  const int tid = threadIdx.x, blk = blockIdx.x;
  stage_WH(tid, blk, rel, a1, w2, Wh, Wl, Hh, Hl);
  __syncthreads();
  const int lane = tid & 63, wave = tid >> 6;
  const int col = lane & 15, quad = lane >> 4;
  const int offA = (wave*16 + col)*72 + quad*8;
  bf16x8 aH0 = *(const bf16x8*)&Wh[offA];
  bf16x8 aH1 = *(const bf16x8*)&Wh[offA+32];
  bf16x8 aL0 = *(const bf16x8*)&Wl[offA];
  bf16x8 aL1 = *(const bf16x8*)&Wl[offA+32];
  float b2v[4];
  #pragma unroll
  for (int r=0;r<4;r++) b2v[r] = b2[wave*16 + quad*4 + r];
  float ssum[4] = {0,0,0,0}, ssq[4] = {0,0,0,0};
  #pragma unroll
  for (int nt=0; nt<8; nt++){
    const int offB = (nt*16 + col)*72 + quad*8;
    bf16x8 bH0 = *(const bf16x8*)&Hh[offB];
    bf16x8 bH1 = *(const bf16x8*)&Hh[offB+32];
    bf16x8 bL0 = *(const bf16x8*)&Hl[offB];
    bf16x8 bL1 = *(const bf16x8*)&Hl[offB+32];
    f32x4 a = {0.f,0.f,0.f,0.f};
    MFMA6(a, bH0, bH1, bL0, bL1)
    #pragma unroll
    for (int r=0;r<4;r++){
      float t = a[r] + b2v[r];
      ssum[r] += t; ssq[r] += t*t;
    }
  }
  #pragma unroll
  for (int off=1; off<16; off<<=1){
    #pragma unroll
    for (int r=0;r<4;r++){
      ssum[r] += __shfl_xor(ssum[r], off);
      ssq[r]  += __shfl_xor(ssq[r],  off);
    }
  }
  if (col == 0){
    const int st = (blk & 7)*64;
    #pragma unroll
    for (int r=0;r<4;r++){
      int ch = wave*16 + quad*4 + r;
      atomicAdd(&gsum8[st+ch], ssum[r]);
      atomicAdd(&gsq8[st+ch],  ssq[r]);
    }
  }
}

// BN2 consts from striped sums: s2 = gamma*istd, c2 = s2*b2 + (beta - mu*s2).
__global__ void stats2_kernel(const float* __restrict__ gsum8, const float* __restrict__ gsq8,
                              const float* __restrict__ b2,
                              const float* __restrict__ gamma, const float* __restrict__ beta,
                              float* __restrict__ s2a, float* __restrict__ c2a){
  const int o = threadIdx.x;
  float s = 0.f, q = 0.f;
  #pragma unroll
  for (int i=0;i<8;i++){ s += gsum8[i*64+o]; q += gsq8[i*64+o]; }
  const float Minv = 1.0f / 524288.0f;
  float mu  = s*Minv;
  float var = q*Minv - mu*mu;
  float istd = rsqrtf(var + 1e-5f);
  float sc = gamma[o]*istd;
  float t2 = beta[o] - mu*sc;
  s2a[o] = sc;
  c2a[o] = fmaf(sc, b2[o], t2);
}

// Pass 3 (MFMA): H1 -> g2 -> (BN2+relu) H2 (overwrites H1 in LDS) -> g3 -> max over k.
__global__ __launch_bounds__(256, 2) void pass3_mfma(
    const float* __restrict__ rel, const float* __restrict__ a1,
    const float* __restrict__ w2, const float* __restrict__ b2,
    const float* __restrict__ s2a, const float* __restrict__ c2a,
    float* __restrict__ out){
  __shared__ alignas(16) u16 Wh[64*72], Wl[64*72];
  __shared__ alignas(16) u16 Hh[128*72], Hl[128*72];
  const int tid = threadIdx.x, blk = blockIdx.x;
  stage_WH(tid, blk, rel, a1, w2, Wh, Wl, Hh, Hl);
  __syncthreads();
  const int lane = tid & 63, wave = tid >> 6;
  const int col = lane & 15, quad = lane >> 4;
  const int offA = (wave*16 + col)*72 + quad*8;
  bf16x8 aH0 = *(const bf16x8*)&Wh[offA];
  bf16x8 aH1 = *(const bf16x8*)&Wh[offA+32];
  bf16x8 aL0 = *(const bf16x8*)&Wl[offA];
  bf16x8 aL1 = *(const bf16x8*)&Wl[offA+32];
  float s2v[4], c2v[4], b2v[4];
  #pragma unroll
  for (int r=0;r<4;r++){
    int ch = wave*16 + quad*4 + r;
    s2v[r] = s2a[ch]; c2v[r] = c2a[ch]; b2v[r] = b2[ch];
  }
  f32x4 acc[8];
  #pragma unroll
  for (int nt=0; nt<8; nt++){
    const int offB = (nt*16 + col)*72 + quad*8;
    bf16x8 bH0 = *(const bf16x8*)&Hh[offB];
    bf16x8 bH1 = *(const bf16x8*)&Hh[offB+32];
    bf16x8 bL0 = *(const bf16x8*)&Hl[offB];
    bf16x8 bL1 = *(const bf16x8*)&Hl[offB+32];
    f32x4 a = {0.f,0.f,0.f,0.f};
    MFMA6(a, bH0, bH1, bL0, bL1)
    acc[nt] = a;
  }
  __syncthreads();   // all layer-2 H reads done -> safe to overwrite with H2
  #pragma unroll
  for (int nt=0; nt<8; nt++){
    const int e = nt*16 + col;
    const int ch0 = wave*16 + quad*4;
    u64 ph = 0, pl = 0;
    #pragma unroll
    for (int r=0;r<4;r++){
      float g = acc[nt][r] + b2v[r];
      float h = fmaxf(fmaf(g, s2v[r], c2v[r]), 0.0f);
      u32 hb = bfh(h);
      u32 lb = bfh(h - __uint_as_float(hb << 16));
      ph |= ((u64)hb) << (16*r);
      pl |= ((u64)lb) << (16*r);
    }
    *(u64*)&Hh[e*72 + ch0] = ph;
    *(u64*)&Hl[e*72 + ch0] = pl;
  }
  __syncthreads();
  #pragma unroll
  for (int nt=0; nt<8; nt++){
    const int offB = (nt*16 + col)*72 + quad*8;
    bf16x8 bH0 = *(const bf16x8*)&Hh[offB];
    bf16x8 bH1 = *(const bf16x8*)&Hh[offB+32];
    bf16x8 bL0 = *(const bf16x8*)&Hl[offB];
    bf16x8 bL1 = *(const bf16x8*)&Hl[offB+32];
    f32x4 a = {0.f,0.f,0.f,0.f};
    MFMA6(a, bH0, bH1, bL0, bL1)
    float m0 = a[0]+b2v[0], m1 = a[1]+b2v[1], m2 = a[2]+b2v[2], m3 = a[3]+b2v[3];
    #pragma unroll
    for (int off=1; off<16; off<<=1){
      m0 = fmaxf(m0, __shfl_xor(m0, off));
      m1 = fmaxf(m1, __shfl_xor(m1, off));
      m2 = fmaxf(m2, __shfl_xor(m2, off));
      m3 = fmaxf(m3, __shfl_xor(m3, off));
    }
    if (col == 0){
      const int gp = blk*8 + nt;
      const int b = gp >> 12, n = gp & 4095;
      const int ch0 = wave*16 + quad*4;
      size_t o0 = (((size_t)b*64 + ch0) << 12) + n;
      out[o0]         = m0;
      out[o0 + 4096]  = m1;
      out[o0 + 8192]  = m2;
      out[o0 + 12288] = m3;
    }
  }
}

extern "C" void kernel_launch(void* const* d_in, const int* in_sizes, int n_in,
                              void* d_out, int out_size, void* d_ws, size_t ws_size,
                              hipStream_t stream){
  const float* xyz   = (const float*)d_in[0];
  const float* w1    = (const float*)d_in[1];
  const float* b1    = (const float*)d_in[2];
  const float* w2    = (const float*)d_in[3];
  const float* b2    = (const float*)d_in[4];
  const float* gamma = (const float*)d_in[5];
  const float* beta  = (const float*)d_in[6];
  float* out = (float*)d_out;
  float* ws  = (float*)d_ws;

  float*  rel   = ws + REL_OFF;
  float4* pts4  = (float4*)(ws + PTS4_OFF);
  float*  mom   = ws + ACC_OFF;        // 16
  float*  gsum8 = mom + 16;            // 512
  float*  gsq8  = mom + 528;           // 512
  float*  a1    = ws + A1_OFF;         // 256
  float*  s2a   = ws + S2_OFF;         // 64
  float*  c2a   = ws + C2_OFF;         // 64

  hipMemsetAsync(mom, 0, 1040*sizeof(float), stream);
  prep_kernel  <<<128,  256, 0, stream>>>(xyz, pts4);
  knn_kernel   <<<512,  512, 0, stream>>>(pts4, rel, mom);
  stats1_kernel<<<1,     64, 0, stream>>>(mom, w1, b1, gamma, beta, a1);
  pass2_mfma   <<<4096, 256, 0, stream>>>(rel, a1, w2, b2, gsum8, gsq8);
  stats2_kernel<<<1,     64, 0, stream>>>(gsum8, gsq8, b2, gamma, beta, s2a, c2a);
  pass3_mfma   <<<4096, 256, 0, stream>>>(rel, a1, w2, b2, s2a, c2a, out);
}